// Round 1
// baseline (2271.548 us; speedup 1.0000x reference)
//
#include <hip/hip_runtime.h>
#include <math.h>

#define EPS 1e-5f
#define INV_H (1.0f / 0.3f)
#define MROWS 32
#define NTHREADS 256

// ---------------------------------------------------------------------------
// prep_kernel: per (sample, column) compute inverse L2 norm over channels.
// If fn_out != null, also write the normalized array (for fx).
// If invn_out != null, write 1/(norm+EPS) (for fy, folded later per-thread).
// idx covers B*HW; coalesced across columns.
// ---------------------------------------------------------------------------
__global__ __launch_bounds__(NTHREADS) void prep_kernel(
    const float* __restrict__ f, float* __restrict__ invn_out,
    float* __restrict__ fn_out, int C, int HW) {
    int idx = blockIdx.x * blockDim.x + threadIdx.x;  // over B*HW
    int b = idx / HW;
    int col = idx - b * HW;
    const float* p = f + (size_t)b * C * HW + col;
    float ssq = 0.f;
    for (int c = 0; c < C; ++c) {
        float v = p[(size_t)c * HW];
        ssq = fmaf(v, v, ssq);
    }
    float inv = 1.0f / (sqrtf(ssq) + EPS);
    if (invn_out) invn_out[idx] = inv;
    if (fn_out) {
        float* q = fn_out + (size_t)b * C * HW + col;
        for (int c = 0; c < C; ++c) q[(size_t)c * HW] = p[(size_t)c * HW] * inv;
    }
}

// ---------------------------------------------------------------------------
// cx_kernel: one block handles MROWS=32 rows of the sim matrix for one sample.
// Pass A: row min of d = 1 - sim. Pass B (recompute dots): row sum of
// exp((1 - d/(dmin+EPS))/h). Then t = wmax/(S+EPS), atomically accumulated
// per sample.
// fxn: pre-normalized (C,HW) per sample -> inner reads are wave-uniform.
// fy: raw; invny folded per-thread after the K loop.
// ---------------------------------------------------------------------------
__global__ __launch_bounds__(NTHREADS) void cx_kernel(
    const float* __restrict__ fxn, const float* __restrict__ fy,
    const float* __restrict__ invny, float* __restrict__ cxacc,
    int C, int HW) {

    __shared__ float sred[MROWS * 4];
    __shared__ float dminS[MROWS];
    __shared__ float dinvS[MROWS];

    const int tid  = threadIdx.x;
    const int lane = tid & 63;
    const int wave = tid >> 6;
    const int rowBlocks = HW / MROWS;
    const int sample = blockIdx.x / rowBlocks;
    const int i0 = (blockIdx.x - sample * rowBlocks) * MROWS;

    const float* fxnS = fxn + (size_t)sample * C * HW;
    const float* fyS  = fy  + (size_t)sample * C * HW;
    const float* inyS = invny + (size_t)sample * HW;

    // ---------------- PASS A: per-row min of d ----------------
    float rmin[MROWS];
#pragma unroll
    for (int m = 0; m < MROWS; ++m) rmin[m] = 1e30f;

    for (int j0 = 0; j0 < HW; j0 += NTHREADS) {
        const int j = j0 + tid;
        const float iny = inyS[j];
        const float* fyp = fyS + j;
        float acc[MROWS];
#pragma unroll
        for (int m = 0; m < MROWS; ++m) acc[m] = 0.f;

#pragma unroll 4
        for (int c = 0; c < C; ++c) {
            float fyv = fyp[(size_t)c * HW];
            const float4* fxr = (const float4*)(fxnS + (size_t)c * HW + i0);
#pragma unroll
            for (int q = 0; q < MROWS / 4; ++q) {
                float4 a = fxr[q];  // wave-uniform address -> scalar/L1 path
                acc[q * 4 + 0] = fmaf(a.x, fyv, acc[q * 4 + 0]);
                acc[q * 4 + 1] = fmaf(a.y, fyv, acc[q * 4 + 1]);
                acc[q * 4 + 2] = fmaf(a.z, fyv, acc[q * 4 + 2]);
                acc[q * 4 + 3] = fmaf(a.w, fyv, acc[q * 4 + 3]);
            }
        }
#pragma unroll
        for (int m = 0; m < MROWS; ++m) {
            float d = 1.0f - acc[m] * iny;
            rmin[m] = fminf(rmin[m], d);
        }
    }

    // reduce min across the 256 threads (per row)
#pragma unroll
    for (int m = 0; m < MROWS; ++m) {
        float v = rmin[m];
        for (int off = 32; off > 0; off >>= 1)
            v = fminf(v, __shfl_xor(v, off));
        if (lane == 0) sred[m * 4 + wave] = v;
    }
    __syncthreads();
    if (tid < MROWS) {
        float v = fminf(fminf(sred[tid * 4 + 0], sred[tid * 4 + 1]),
                        fminf(sred[tid * 4 + 2], sred[tid * 4 + 3]));
        dminS[tid] = v;
        dinvS[tid] = 1.0f / (v + EPS);
    }
    __syncthreads();

    float dinv[MROWS];
#pragma unroll
    for (int m = 0; m < MROWS; ++m) dinv[m] = dinvS[m];

    // ---------------- PASS B: per-row sum of exp ----------------
    float ssum[MROWS];
#pragma unroll
    for (int m = 0; m < MROWS; ++m) ssum[m] = 0.f;

    for (int j0 = 0; j0 < HW; j0 += NTHREADS) {
        const int j = j0 + tid;
        const float iny = inyS[j];
        const float* fyp = fyS + j;
        float acc[MROWS];
#pragma unroll
        for (int m = 0; m < MROWS; ++m) acc[m] = 0.f;

#pragma unroll 4
        for (int c = 0; c < C; ++c) {
            float fyv = fyp[(size_t)c * HW];
            const float4* fxr = (const float4*)(fxnS + (size_t)c * HW + i0);
#pragma unroll
            for (int q = 0; q < MROWS / 4; ++q) {
                float4 a = fxr[q];
                acc[q * 4 + 0] = fmaf(a.x, fyv, acc[q * 4 + 0]);
                acc[q * 4 + 1] = fmaf(a.y, fyv, acc[q * 4 + 1]);
                acc[q * 4 + 2] = fmaf(a.z, fyv, acc[q * 4 + 2]);
                acc[q * 4 + 3] = fmaf(a.w, fyv, acc[q * 4 + 3]);
            }
        }
#pragma unroll
        for (int m = 0; m < MROWS; ++m) {
            float d = 1.0f - acc[m] * iny;
            ssum[m] += __expf((1.0f - d * dinv[m]) * INV_H);
        }
    }

    // reduce sum across threads (per row)
#pragma unroll
    for (int m = 0; m < MROWS; ++m) {
        float v = ssum[m];
        for (int off = 32; off > 0; off >>= 1)
            v += __shfl_xor(v, off);
        if (lane == 0) sred[m * 4 + wave] = v;
    }
    __syncthreads();
    if (tid < MROWS) {
        float S = sred[tid * 4 + 0] + sred[tid * 4 + 1] +
                  sred[tid * 4 + 2] + sred[tid * 4 + 3];
        float dmin = dminS[tid];
        float wmax = __expf((1.0f - dmin * dinvS[tid]) * INV_H);
        float t = wmax / (S + EPS);
        atomicAdd(&cxacc[sample], t);
    }
}

// ---------------------------------------------------------------------------
// finalize: cx per sample = cxs[s]/HW; loss = mean over samples of
// -log(cx+EPS) per layer; output = (L1+L2)/2.
// ---------------------------------------------------------------------------
__global__ void finalize_kernel(const float* __restrict__ cxs,
                                float* __restrict__ out) {
    if (threadIdx.x == 0 && blockIdx.x == 0) {
        float l1 = 0.f, l2 = 0.f;
        for (int s = 0; s < 8; ++s)
            l1 += -logf(cxs[s] * (1.0f / 4096.0f) + EPS);
        for (int s = 0; s < 8; ++s)
            l2 += -logf(cxs[8 + s] * (1.0f / 1024.0f) + EPS);
        out[0] = 0.5f * (l1 * 0.125f + l2 * 0.125f);
    }
}

extern "C" void kernel_launch(void* const* d_in, const int* in_sizes, int n_in,
                              void* d_out, int out_size, void* d_ws, size_t ws_size,
                              hipStream_t stream) {
    const float* fx1 = (const float*)d_in[0];  // (8,128,64,64)
    const float* fy1 = (const float*)d_in[1];
    const float* fx2 = (const float*)d_in[2];  // (8,256,32,32)
    const float* fy2 = (const float*)d_in[3];
    float* out = (float*)d_out;

    const int B = 8;
    const int C1 = 128, HW1 = 4096;
    const int C2 = 256, HW2 = 1024;

    float* ws = (float*)d_ws;
    float* cxs    = ws;                         // 16 floats (8 per layer)
    float* invny1 = ws + 16;                    // B*HW1
    float* invny2 = invny1 + B * HW1;           // B*HW2
    float* fxn1   = invny2 + B * HW2;           // B*C1*HW1 (normalized fx1)
    float* fxn2   = fxn1 + (size_t)B * C1 * HW1;  // B*C2*HW2
    // total ws: ~25.3 MB of floats

    hipMemsetAsync(cxs, 0, 16 * sizeof(float), stream);

    prep_kernel<<<B * HW1 / NTHREADS, NTHREADS, 0, stream>>>(fx1, nullptr, fxn1, C1, HW1);
    prep_kernel<<<B * HW1 / NTHREADS, NTHREADS, 0, stream>>>(fy1, invny1, nullptr, C1, HW1);
    prep_kernel<<<B * HW2 / NTHREADS, NTHREADS, 0, stream>>>(fx2, nullptr, fxn2, C2, HW2);
    prep_kernel<<<B * HW2 / NTHREADS, NTHREADS, 0, stream>>>(fy2, invny2, nullptr, C2, HW2);

    cx_kernel<<<B * (HW1 / MROWS), NTHREADS, 0, stream>>>(fxn1, fy1, invny1, cxs + 0, C1, HW1);
    cx_kernel<<<B * (HW2 / MROWS), NTHREADS, 0, stream>>>(fxn2, fy2, invny2, cxs + 8, C2, HW2);

    finalize_kernel<<<1, 64, 0, stream>>>(cxs, out);
}

// Round 2
// 472.233 us; speedup vs baseline: 4.8102x; 4.8102x over previous
//
#include <hip/hip_runtime.h>
#include <math.h>

#define EPS 1e-5f
#define KEXP 4.8089834696298780f  // log2(e) / 0.3  (exp(x/h) == exp2(x*KEXP))

typedef short short8 __attribute__((ext_vector_type(8)));
typedef float f32x4  __attribute__((ext_vector_type(4)));

static __device__ __forceinline__ unsigned short f2bf(float x) {
  unsigned int b = __float_as_uint(x);
  b += 0x7FFFu + ((b >> 16) & 1u);   // round-to-nearest-even
  return (unsigned short)(b >> 16);
}

// ---------------------------------------------------------------------------
// prep: per column j compute 1/(||col||+EPS), normalize, cast bf16, and write
// MFMA-fragment-blocked layout:
//   element (j,c) -> uint4 index ((j>>4)*KC + (c>>5))*64 + ((c>>3)&3)*16 + (j&15)
// (one uint4 = 8 consecutive-c bf16 = one lane's 16B fragment slice).
// A 16x16x32 A/B fragment for (j-tile jb, k-chunk kc) is then chunk + lane*16B.
// ---------------------------------------------------------------------------
__global__ __launch_bounds__(256) void prep_kernel(
    const float* __restrict__ f, uint4* __restrict__ out, int C, int HW) {
  int idx = blockIdx.x * 256 + threadIdx.x;  // over B*HW
  int b = idx / HW, j = idx - b * HW;
  const float* p = f + (size_t)b * C * HW + j;
  float ssq = 0.f;
  for (int c = 0; c < C; ++c) { float v = p[(size_t)c * HW]; ssq = fmaf(v, v, ssq); }
  float inv = 1.0f / (sqrtf(ssq) + EPS);
  const int KC = C >> 5;
  uint4* ob = out + (size_t)b * (HW >> 4) * KC * 64 + (size_t)(j >> 4) * KC * 64 + (j & 15);
  for (int c0 = 0; c0 < C; c0 += 8) {
    unsigned int w[4];
#pragma unroll
    for (int h = 0; h < 4; ++h) {
      float v0 = p[(size_t)(c0 + 2 * h) * HW] * inv;
      float v1 = p[(size_t)(c0 + 2 * h + 1) * HW] * inv;
      w[h] = (unsigned int)f2bf(v0) | ((unsigned int)f2bf(v1) << 16);
    }
    uint4 pk = make_uint4(w[0], w[1], w[2], w[3]);
    ob[(size_t)(c0 >> 5) * 64 + ((c0 >> 3) & 3) * 16] = pk;
  }
}

// ---------------------------------------------------------------------------
// cx_mfma: block = 4 waves, all on the same i-range (TI tiles of 16 cols of fx),
// j-tiles interleaved across waves (each step: 2 consecutive 16-j tiles/wave).
// A (arg0, M rows of D) = fy j-tile; B (arg1, N cols of D) = fx i-tile held in
// registers for the whole kernel. Pass A: row max of sim (dmin = 1-smax).
// Pass B: recompute dots, accumulate sum of exp2(c0 + s*c1).
// Row reductions: per-lane over regs -> shfl over quads -> LDS over waves.
// ---------------------------------------------------------------------------
template <int HW, int C, int TI>
__global__ __launch_bounds__(256) void cx_mfma(
    const uint4* __restrict__ fxB, const uint4* __restrict__ fyB,
    float* __restrict__ cxacc) {
  constexpr int KC = C / 32;       // K-chunks of 32
  constexpr int JB = HW / 16;      // 16-wide j tiles
  constexpr int IPB = HW / (TI * 16);  // i-blocks per sample
  const int lane = threadIdx.x & 63;
  const int wv = threadIdx.x >> 6;
  const int l15 = lane & 15;
  const int sample = blockIdx.x / IPB;
  const int ib0 = (blockIdx.x % IPB) * TI;
  const size_t sOff = (size_t)sample * JB * KC * 64;
  const uint4* fx = fxB + sOff;
  const uint4* fy = fyB + sOff;

  // persistent fx (B-operand) fragments: lane -> fx[i=ib*16+l15][k=kc*32+quad*8+0..7]
  short8 bf[TI][KC];
#pragma unroll
  for (int ti = 0; ti < TI; ++ti)
#pragma unroll
    for (int kc = 0; kc < KC; ++kc) {
      uint4 t = fx[(size_t)((ib0 + ti) * KC + kc) * 64 + lane];
      bf[ti][kc] = *(short8*)&t;
    }

  __shared__ float red[4][TI][16];

  // ---------------- pass A: row max of sim over all j ----------------
  float smax[TI];
#pragma unroll
  for (int ti = 0; ti < TI; ++ti) smax[ti] = -1e30f;

  for (int s = 0; s < JB / 8; ++s) {
    const int jb0 = s * 8 + wv * 2;
    f32x4 acc[TI][2];
#pragma unroll
    for (int ti = 0; ti < TI; ++ti)
#pragma unroll
      for (int tj = 0; tj < 2; ++tj)
#pragma unroll
        for (int r = 0; r < 4; ++r) acc[ti][tj][r] = 0.f;
#pragma unroll
    for (int kc = 0; kc < KC; ++kc) {
      uint4 t0 = fy[(size_t)(jb0 * KC + kc) * 64 + lane];
      uint4 t1 = fy[(size_t)((jb0 + 1) * KC + kc) * 64 + lane];
      short8 a0 = *(short8*)&t0;
      short8 a1 = *(short8*)&t1;
#pragma unroll
      for (int ti = 0; ti < TI; ++ti) {
        acc[ti][0] = __builtin_amdgcn_mfma_f32_16x16x32_bf16(a0, bf[ti][kc], acc[ti][0], 0, 0, 0);
        acc[ti][1] = __builtin_amdgcn_mfma_f32_16x16x32_bf16(a1, bf[ti][kc], acc[ti][1], 0, 0, 0);
      }
    }
#pragma unroll
    for (int ti = 0; ti < TI; ++ti)
#pragma unroll
      for (int tj = 0; tj < 2; ++tj)
#pragma unroll
        for (int r = 0; r < 4; ++r) smax[ti] = fmaxf(smax[ti], acc[ti][tj][r]);
  }
#pragma unroll
  for (int ti = 0; ti < TI; ++ti) {
    float v = smax[ti];
    v = fmaxf(v, __shfl_xor(v, 16));
    v = fmaxf(v, __shfl_xor(v, 32));
    if (lane < 16) red[wv][ti][l15] = v;
  }
  __syncthreads();
#pragma unroll
  for (int ti = 0; ti < TI; ++ti)
    smax[ti] = fmaxf(fmaxf(red[0][ti][l15], red[1][ti][l15]),
                     fmaxf(red[2][ti][l15], red[3][ti][l15]));
  __syncthreads();  // red gets reused by pass B

  float c0v[TI], c1v[TI];
#pragma unroll
  for (int ti = 0; ti < TI; ++ti) {
    float dmin = 1.0f - smax[ti];
    float dinv = 1.0f / (dmin + EPS);
    c1v[ti] = dinv * KEXP;
    c0v[ti] = (1.0f - dinv) * KEXP;
  }

  // ---------------- pass B: row sum of w = exp2(c0 + s*c1) ----------------
  float ssum[TI];
#pragma unroll
  for (int ti = 0; ti < TI; ++ti) ssum[ti] = 0.f;

  for (int s = 0; s < JB / 8; ++s) {
    const int jb0 = s * 8 + wv * 2;
    f32x4 acc[TI][2];
#pragma unroll
    for (int ti = 0; ti < TI; ++ti)
#pragma unroll
      for (int tj = 0; tj < 2; ++tj)
#pragma unroll
        for (int r = 0; r < 4; ++r) acc[ti][tj][r] = 0.f;
#pragma unroll
    for (int kc = 0; kc < KC; ++kc) {
      uint4 t0 = fy[(size_t)(jb0 * KC + kc) * 64 + lane];
      uint4 t1 = fy[(size_t)((jb0 + 1) * KC + kc) * 64 + lane];
      short8 a0 = *(short8*)&t0;
      short8 a1 = *(short8*)&t1;
#pragma unroll
      for (int ti = 0; ti < TI; ++ti) {
        acc[ti][0] = __builtin_amdgcn_mfma_f32_16x16x32_bf16(a0, bf[ti][kc], acc[ti][0], 0, 0, 0);
        acc[ti][1] = __builtin_amdgcn_mfma_f32_16x16x32_bf16(a1, bf[ti][kc], acc[ti][1], 0, 0, 0);
      }
    }
#pragma unroll
    for (int ti = 0; ti < TI; ++ti)
#pragma unroll
      for (int tj = 0; tj < 2; ++tj)
#pragma unroll
        for (int r = 0; r < 4; ++r)
          ssum[ti] += __builtin_amdgcn_exp2f(fmaf(acc[ti][tj][r], c1v[ti], c0v[ti]));
  }
#pragma unroll
  for (int ti = 0; ti < TI; ++ti) {
    float v = ssum[ti];
    v += __shfl_xor(v, 16);
    v += __shfl_xor(v, 32);
    if (lane < 16) red[wv][ti][l15] = v;
  }
  __syncthreads();
  if (wv == 0) {
    float t = 0.f;
#pragma unroll
    for (int ti = 0; ti < TI; ++ti) {
      float S = red[0][ti][l15] + red[1][ti][l15] + red[2][ti][l15] + red[3][ti][l15];
      float wmx = __builtin_amdgcn_exp2f(fmaf(smax[ti], c1v[ti], c0v[ti]));
      t += wmx / (S + EPS);
    }
    t += __shfl_xor(t, 1);
    t += __shfl_xor(t, 2);
    t += __shfl_xor(t, 4);
    t += __shfl_xor(t, 8);
    if (lane == 0) atomicAdd(&cxacc[sample], t);
  }
}

__global__ void finalize_kernel(const float* __restrict__ cxs,
                                float* __restrict__ out) {
  if (threadIdx.x == 0 && blockIdx.x == 0) {
    float l1 = 0.f, l2 = 0.f;
    for (int s = 0; s < 8; ++s)
      l1 += -logf(cxs[s] * (1.0f / 4096.0f) + EPS);
    for (int s = 0; s < 8; ++s)
      l2 += -logf(cxs[8 + s] * (1.0f / 1024.0f) + EPS);
    out[0] = 0.5f * (l1 * 0.125f + l2 * 0.125f);
  }
}

extern "C" void kernel_launch(void* const* d_in, const int* in_sizes, int n_in,
                              void* d_out, int out_size, void* d_ws, size_t ws_size,
                              hipStream_t stream) {
  const float* fx1 = (const float*)d_in[0];  // (8,128,64,64)
  const float* fy1 = (const float*)d_in[1];
  const float* fx2 = (const float*)d_in[2];  // (8,256,32,32)
  const float* fy2 = (const float*)d_in[3];
  float* out = (float*)d_out;

  const int B = 8;
  const int C1 = 128, HW1 = 4096;
  const int C2 = 256, HW2 = 1024;

  // ws layout: 16-float accumulator, then 4 blocked bf16 arrays (16B aligned)
  float* cxs = (float*)d_ws;
  uint4* fx1B = (uint4*)((char*)d_ws + 64);
  const size_t n1 = (size_t)B * (HW1 / 16) * (C1 / 32) * 64;  // uint4 count: 512K (8MB)
  const size_t n2 = (size_t)B * (HW2 / 16) * (C2 / 32) * 64;  // 256K (4MB)
  uint4* fy1B = fx1B + n1;
  uint4* fx2B = fy1B + n1;
  uint4* fy2B = fx2B + n2;  // total 24 MB + 64 B

  hipMemsetAsync(cxs, 0, 16 * sizeof(float), stream);

  prep_kernel<<<B * HW1 / 256, 256, 0, stream>>>(fx1, fx1B, C1, HW1);
  prep_kernel<<<B * HW1 / 256, 256, 0, stream>>>(fy1, fy1B, C1, HW1);
  prep_kernel<<<B * HW2 / 256, 256, 0, stream>>>(fx2, fx2B, C2, HW2);
  prep_kernel<<<B * HW2 / 256, 256, 0, stream>>>(fy2, fy2B, C2, HW2);

  // layer1: TI=2 (32 i/block) -> 8*128 = 1024 blocks
  cx_mfma<4096, 128, 2><<<B * (HW1 / 32), 256, 0, stream>>>(fx1B, fy1B, cxs + 0);
  // layer2: TI=1 (16 i/block) -> 8*64 = 512 blocks
  cx_mfma<1024, 256, 1><<<B * (HW2 / 16), 256, 0, stream>>>(fx2B, fy2B, cxs + 8);

  finalize_kernel<<<1, 64, 0, stream>>>(cxs, out);
}

// Round 3
// 210.458 us; speedup vs baseline: 10.7934x; 2.2438x over previous
//
#include <hip/hip_runtime.h>
#include <math.h>

#define EPS 1e-5f
#define KEXP 4.8089834696298780f  // log2(e)/0.3 : exp(x/h) == exp2(x*KEXP)

typedef short short8 __attribute__((ext_vector_type(8)));
typedef float f32x4  __attribute__((ext_vector_type(4)));

static __device__ __forceinline__ unsigned short f2bf(float x) {
  unsigned int b = __float_as_uint(x);
  b += 0x7FFFu + ((b >> 16) & 1u);  // RNE
  return (unsigned short)(b >> 16);
}

// encoded-unsigned order-preserving float key for atomicMin
static __device__ __forceinline__ unsigned encf(float f) {
  unsigned b = __float_as_uint(f);
  return (b & 0x80000000u) ? ~b : (b | 0x80000000u);
}
static __device__ __forceinline__ float decf(unsigned u) {
  return (u & 0x80000000u) ? __uint_as_float(u & 0x7FFFFFFFu)
                           : __uint_as_float(~u);
}

// ---------------------------------------------------------------------------
// prep: normalize column j (over C), cast bf16, write MFMA-fragment-blocked:
//   (j,c) -> uint4 idx ((j>>4)*KC + (c>>5))*64 + ((c>>3)&3)*16 + (j&15)
// so a 16x16x32 fragment (j-tile, k-chunk) is chunk_base + lane*16B.
// ---------------------------------------------------------------------------
template <int C, int HW>
__device__ __forceinline__ void prep_body(const float* __restrict__ f,
                                          uint4* __restrict__ out, int idx) {
  int b = idx / HW, j = idx - b * HW;
  const float* p = f + (size_t)b * C * HW + j;
  float ssq = 0.f;
  for (int c = 0; c < C; ++c) { float v = p[(size_t)c * HW]; ssq = fmaf(v, v, ssq); }
  float inv = 1.0f / (sqrtf(ssq) + EPS);
  constexpr int KC = C >> 5;
  uint4* ob = out + (size_t)b * (HW >> 4) * KC * 64 + (size_t)(j >> 4) * KC * 64 + (j & 15);
  for (int c0 = 0; c0 < C; c0 += 8) {
    unsigned w[4];
#pragma unroll
    for (int h = 0; h < 4; ++h) {
      float v0 = p[(size_t)(c0 + 2 * h) * HW] * inv;
      float v1 = p[(size_t)(c0 + 2 * h + 1) * HW] * inv;
      w[h] = (unsigned)f2bf(v0) | ((unsigned)f2bf(v1) << 16);
    }
    ob[(size_t)(c0 >> 5) * 64 + ((c0 >> 3) & 3) * 16] = make_uint4(w[0], w[1], w[2], w[3]);
  }
}

__global__ __launch_bounds__(256) void prep_all(
    const float* __restrict__ fx1, uint4* __restrict__ fx1B,
    const float* __restrict__ fy1, uint4* __restrict__ fy1B,
    const float* __restrict__ fx2, uint4* __restrict__ fx2B,
    const float* __restrict__ fy2, uint4* __restrict__ fy2B) {
  int bid = blockIdx.x;
  if (bid < 128)       prep_body<128, 4096>(fx1, fx1B, bid * 256 + threadIdx.x);
  else if (bid < 256)  prep_body<128, 4096>(fy1, fy1B, (bid - 128) * 256 + threadIdx.x);
  else if (bid < 288)  prep_body<256, 1024>(fx2, fx2B, (bid - 256) * 256 + threadIdx.x);
  else                 prep_body<256, 1024>(fy2, fy2B, (bid - 288) * 256 + threadIdx.x);
}

// ---------------------------------------------------------------------------
// passA: per (sample, i-block of TI*16, j-slice) compute partial row-min of
// d = 1 - sim over the slice; combine via encoded atomicMin per i.
// A (rows of D) = fy j-tile streamed; B (cols) = fx, persistent in registers.
// ---------------------------------------------------------------------------
template <int HW, int C, int TI, int JSPLIT>
__global__ __launch_bounds__(256, 4) void passA(
    const uint4* __restrict__ fxB, const uint4* __restrict__ fyB,
    unsigned* __restrict__ dminEnc) {
  constexpr int KC = C / 32;
  constexpr int JB = HW / 16;
  constexpr int IPB = HW / (TI * 16);
  constexpr int JPS = JB / JSPLIT;      // j-tiles per slice
  constexpr int TPS = JPS / 4;          // j-tiles per wave
  const int lane = threadIdx.x & 63, wv = threadIdx.x >> 6, l15 = lane & 15;
  const int blk = blockIdx.x;
  const int sample = blk / (IPB * JSPLIT);
  const int rem = blk % (IPB * JSPLIT);
  const int ib0 = (rem / JSPLIT) * TI;
  const int jt0 = (rem % JSPLIT) * JPS;
  const size_t sOff = (size_t)sample * JB * KC * 64;
  const uint4* fx = fxB + sOff;
  const uint4* fy = fyB + sOff;

  short8 bf[TI][KC];
#pragma unroll
  for (int ti = 0; ti < TI; ++ti)
#pragma unroll
    for (int kc = 0; kc < KC; ++kc) {
      uint4 t = fx[(size_t)((ib0 + ti) * KC + kc) * 64 + lane];
      bf[ti][kc] = *(short8*)&t;
    }

  float smax[TI];
#pragma unroll
  for (int ti = 0; ti < TI; ++ti) smax[ti] = -1e30f;

  for (int s = 0; s < TPS; ++s) {
    const int jt = jt0 + s * 4 + wv;
    uint4 af[KC];
#pragma unroll
    for (int kc = 0; kc < KC; ++kc) af[kc] = fy[(size_t)(jt * KC + kc) * 64 + lane];
    f32x4 acc[TI];
#pragma unroll
    for (int ti = 0; ti < TI; ++ti)
#pragma unroll
      for (int r = 0; r < 4; ++r) acc[ti][r] = 0.f;
#pragma unroll
    for (int kc = 0; kc < KC; ++kc) {
      short8 a = *(short8*)&af[kc];
#pragma unroll
      for (int ti = 0; ti < TI; ++ti)
        acc[ti] = __builtin_amdgcn_mfma_f32_16x16x32_bf16(a, bf[ti][kc], acc[ti], 0, 0, 0);
    }
#pragma unroll
    for (int ti = 0; ti < TI; ++ti)
#pragma unroll
      for (int r = 0; r < 4; ++r) smax[ti] = fmaxf(smax[ti], acc[ti][r]);
  }

  __shared__ float red[4][TI][16];
#pragma unroll
  for (int ti = 0; ti < TI; ++ti) {
    float v = smax[ti];
    v = fmaxf(v, __shfl_xor(v, 16));
    v = fmaxf(v, __shfl_xor(v, 32));
    if (lane < 16) red[wv][ti][l15] = v;
  }
  __syncthreads();
  if (threadIdx.x < TI * 16) {
    const int ti = threadIdx.x >> 4, il = threadIdx.x & 15;
    float v = fmaxf(fmaxf(red[0][ti][il], red[1][ti][il]),
                    fmaxf(red[2][ti][il], red[3][ti][il]));
    float d = 1.0f - v;  // min d over slice == 1 - max sim
    atomicMin(&dminEnc[(size_t)sample * HW + (ib0 + ti) * 16 + il], encf(d));
  }
}

// ---------------------------------------------------------------------------
// passB: recompute dots, accumulate partial sum_j exp2(c0 + sim*c1) per i.
// ---------------------------------------------------------------------------
template <int HW, int C, int TI, int JSPLIT>
__global__ __launch_bounds__(256, 4) void passB(
    const uint4* __restrict__ fxB, const uint4* __restrict__ fyB,
    const unsigned* __restrict__ dminEnc, float* __restrict__ Ssum) {
  constexpr int KC = C / 32;
  constexpr int JB = HW / 16;
  constexpr int IPB = HW / (TI * 16);
  constexpr int JPS = JB / JSPLIT;
  constexpr int TPS = JPS / 4;
  const int lane = threadIdx.x & 63, wv = threadIdx.x >> 6, l15 = lane & 15;
  const int blk = blockIdx.x;
  const int sample = blk / (IPB * JSPLIT);
  const int rem = blk % (IPB * JSPLIT);
  const int ib0 = (rem / JSPLIT) * TI;
  const int jt0 = (rem % JSPLIT) * JPS;
  const size_t sOff = (size_t)sample * JB * KC * 64;
  const uint4* fx = fxB + sOff;
  const uint4* fy = fyB + sOff;

  short8 bf[TI][KC];
#pragma unroll
  for (int ti = 0; ti < TI; ++ti)
#pragma unroll
    for (int kc = 0; kc < KC; ++kc) {
      uint4 t = fx[(size_t)((ib0 + ti) * KC + kc) * 64 + lane];
      bf[ti][kc] = *(short8*)&t;
    }

  float c0v[TI], c1v[TI];
#pragma unroll
  for (int ti = 0; ti < TI; ++ti) {
    float dmin = decf(dminEnc[(size_t)sample * HW + (ib0 + ti) * 16 + l15]);
    float dinv = 1.0f / (dmin + EPS);
    c1v[ti] = dinv * KEXP;            // sim coefficient (d = 1 - sim)
    c0v[ti] = (1.0f - dinv) * KEXP;
  }

  float ssum[TI];
#pragma unroll
  for (int ti = 0; ti < TI; ++ti) ssum[ti] = 0.f;

  for (int s = 0; s < TPS; ++s) {
    const int jt = jt0 + s * 4 + wv;
    uint4 af[KC];
#pragma unroll
    for (int kc = 0; kc < KC; ++kc) af[kc] = fy[(size_t)(jt * KC + kc) * 64 + lane];
    f32x4 acc[TI];
#pragma unroll
    for (int ti = 0; ti < TI; ++ti)
#pragma unroll
      for (int r = 0; r < 4; ++r) acc[ti][r] = 0.f;
#pragma unroll
    for (int kc = 0; kc < KC; ++kc) {
      short8 a = *(short8*)&af[kc];
#pragma unroll
      for (int ti = 0; ti < TI; ++ti)
        acc[ti] = __builtin_amdgcn_mfma_f32_16x16x32_bf16(a, bf[ti][kc], acc[ti], 0, 0, 0);
    }
#pragma unroll
    for (int ti = 0; ti < TI; ++ti)
#pragma unroll
      for (int r = 0; r < 4; ++r)
        ssum[ti] += __builtin_amdgcn_exp2f(fmaf(acc[ti][r], c1v[ti], c0v[ti]));
  }

  __shared__ float red[4][TI][16];
#pragma unroll
  for (int ti = 0; ti < TI; ++ti) {
    float v = ssum[ti];
    v += __shfl_xor(v, 16);
    v += __shfl_xor(v, 32);
    if (lane < 16) red[wv][ti][l15] = v;
  }
  __syncthreads();
  if (threadIdx.x < TI * 16) {
    const int ti = threadIdx.x >> 4, il = threadIdx.x & 15;
    float v = red[0][ti][il] + red[1][ti][il] + red[2][ti][il] + red[3][ti][il];
    atomicAdd(&Ssum[(size_t)sample * HW + (ib0 + ti) * 16 + il], v);
  }
}

// ---------------------------------------------------------------------------
// reduce_cx: one block per sample; t_i = wmax/(S+EPS); cxs[s] = sum_i t_i.
// blocks 0..7 -> layer1, 8..15 -> layer2.
// ---------------------------------------------------------------------------
__global__ __launch_bounds__(256) void reduce_cx(
    const unsigned* __restrict__ dE1, const float* __restrict__ S1,
    const unsigned* __restrict__ dE2, const float* __restrict__ S2,
    float* __restrict__ cxs) {
  const int s = blockIdx.x;
  const unsigned* dE;
  const float* Sp;
  int HW;
  if (s < 8) { dE = dE1 + (size_t)s * 4096; Sp = S1 + (size_t)s * 4096; HW = 4096; }
  else       { dE = dE2 + (size_t)(s - 8) * 1024; Sp = S2 + (size_t)(s - 8) * 1024; HW = 1024; }
  float t = 0.f;
  for (int i = threadIdx.x; i < HW; i += 256) {
    float dmin = decf(dE[i]);
    float dinv = 1.0f / (dmin + EPS);
    float wmx = __builtin_amdgcn_exp2f((1.0f - dmin * dinv) * KEXP);
    t += wmx / (Sp[i] + EPS);
  }
  __shared__ float red[4];
  t += __shfl_xor(t, 1);  t += __shfl_xor(t, 2);  t += __shfl_xor(t, 4);
  t += __shfl_xor(t, 8);  t += __shfl_xor(t, 16); t += __shfl_xor(t, 32);
  if ((threadIdx.x & 63) == 0) red[threadIdx.x >> 6] = t;
  __syncthreads();
  if (threadIdx.x == 0) cxs[s] = red[0] + red[1] + red[2] + red[3];
}

__global__ void loss_kernel(const float* __restrict__ cxs, float* __restrict__ out) {
  if (threadIdx.x == 0 && blockIdx.x == 0) {
    float l1 = 0.f, l2 = 0.f;
    for (int s = 0; s < 8; ++s) l1 += -logf(cxs[s] * (1.0f / 4096.0f) + EPS);
    for (int s = 0; s < 8; ++s) l2 += -logf(cxs[8 + s] * (1.0f / 1024.0f) + EPS);
    out[0] = 0.5f * (l1 * 0.125f + l2 * 0.125f);
  }
}

extern "C" void kernel_launch(void* const* d_in, const int* in_sizes, int n_in,
                              void* d_out, int out_size, void* d_ws, size_t ws_size,
                              hipStream_t stream) {
  const float* fx1 = (const float*)d_in[0];  // (8,128,64,64)
  const float* fy1 = (const float*)d_in[1];
  const float* fx2 = (const float*)d_in[2];  // (8,256,32,32)
  const float* fy2 = (const float*)d_in[3];
  float* out = (float*)d_out;

  const int B = 8, HW1 = 4096, HW2 = 1024;

  // ws layout (16B-aligned regions):
  char* w = (char*)d_ws;
  float*    cxs  = (float*)w;                       // 16 f
  unsigned* dE1  = (unsigned*)(w + 4096);           // 8*4096 u32 = 128 KB
  unsigned* dE2  = dE1 + (size_t)B * HW1;           // 32 KB
  float*    S1   = (float*)(dE2 + (size_t)B * HW2); // 128 KB
  float*    S2   = S1 + (size_t)B * HW1;            // 32 KB
  uint4*    fx1B = (uint4*)((char*)(S2 + (size_t)B * HW2) + 2048);
  const size_t n1 = (size_t)B * (HW1 / 16) * (128 / 32) * 64;  // 8 MB
  const size_t n2 = (size_t)B * (HW2 / 16) * (256 / 32) * 64;  // 4 MB
  uint4* fy1B = fx1B + n1;
  uint4* fx2B = fy1B + n1;
  uint4* fy2B = fx2B + n2;   // total ~24.4 MB

  // dmin keys init to encoded +max (0xFFFFFFFF); S sums to 0. One memset each
  // (dE1,dE2 contiguous; S1,S2 contiguous).
  hipMemsetAsync(dE1, 0xFF, (size_t)B * (HW1 + HW2) * 4, stream);
  hipMemsetAsync(S1, 0x00, (size_t)B * (HW1 + HW2) * 4, stream);

  prep_all<<<320, 256, 0, stream>>>(fx1, fx1B, fy1, fy1B, fx2, fx2B, fy2, fy2B);

  // layer1: TI=4 (i-width 64), JSPLIT=2 -> 8*64*2 = 1024 blocks
  passA<4096, 128, 4, 2><<<1024, 256, 0, stream>>>(fx1B, fy1B, dE1);
  // layer2: TI=2 (i-width 32), JSPLIT=4 -> 8*32*4 = 1024 blocks
  passA<1024, 256, 2, 4><<<1024, 256, 0, stream>>>(fx2B, fy2B, dE2);

  passB<4096, 128, 4, 2><<<1024, 256, 0, stream>>>(fx1B, fy1B, dE1, S1);
  passB<1024, 256, 2, 4><<<1024, 256, 0, stream>>>(fx2B, fy2B, dE2, S2);

  reduce_cx<<<16, 256, 0, stream>>>(dE1, S1, dE2, S2, cxs);
  loss_kernel<<<1, 64, 0, stream>>>(cxs, out);
}